// Round 4
// baseline (532.586 us; speedup 1.0000x reference)
//
#include <hip/hip_runtime.h>
#include <cstdint>
#include <cstddef>

// Problem constants: B=128, L=64, F=3072, D=1024, CV=512, CN=1024, MAX_K=8
typedef unsigned short u16;
typedef __attribute__((ext_vector_type(8))) short short8;   // 8 x bf16 (4 VGPRs)
typedef __attribute__((ext_vector_type(4))) float f32x4;    // MFMA accumulator

static __device__ __forceinline__ float bf2f(u16 h) {
  union { unsigned u; float f; } a; a.u = ((unsigned)h) << 16; return a.f;
}
static __device__ __forceinline__ u16 f2bf(float x) {
  union { float f; unsigned u; } a; a.f = x;
  return (u16)((a.u + 0x7fffu + ((a.u >> 16) & 1u)) >> 16);  // RNE
}

// async global->LDS, 16B per lane. LDS dest is wave-uniform base + lane*16.
#define GLDS16(gp, lp)                                                          \
  __builtin_amdgcn_global_load_lds(                                             \
      (const __attribute__((address_space(1))) void*)(gp),                      \
      (__attribute__((address_space(3))) void*)(lp), 16, 0, 0)

// ------------------------------------------------------------- merged prep
__global__ void prep_all(const float* __restrict__ inputs, u16* __restrict__ Xbf,
                         const float* __restrict__ W0, const float* __restrict__ W1,
                         const float* __restrict__ W2, u16* __restrict__ Wt,
                         const float* __restrict__ Kv, const float* __restrict__ bv,
                         const float* __restrict__ g_v, const float* __restrict__ beta_v,
                         const float* __restrict__ mean_v, const float* __restrict__ var_v,
                         u16* __restrict__ KVt, float* __restrict__ biasv,
                         const float* __restrict__ Kn, const float* __restrict__ bnb,
                         const float* __restrict__ g_n, const float* __restrict__ beta_n,
                         const float* __restrict__ mean_n, const float* __restrict__ var_n,
                         u16* __restrict__ KNt, float* __restrict__ biasn,
                         u16* __restrict__ e1pad) {
  __shared__ float tile[32][33];
  const int id = blockIdx.x;
  const int tid = threadIdx.x;
  if (id < 24576) {                       // cast: float4 -> 4x bf16
    const int i = id * 256 + tid;         // < 6291456 exactly
    float4 v = ((const float4*)inputs)[i];
    ushort4 o;
    o.x = f2bf(v.x); o.y = f2bf(v.y); o.z = f2bf(v.z); o.w = f2bf(v.w);
    ((ushort4*)Xbf)[i] = o;
  } else if (id < 33792) {                // transpose W
    const int idd = id - 24576;
    const int kb = (idd % 96) * 32;
    const int jb = (idd / 96) * 32;
    const int tx = tid & 31, ty = tid >> 5;
    const int w = jb >> 10;
    const float* W = (w == 0) ? W0 : ((w == 1) ? W1 : W2);
    const int nb = jb & 1023;
    for (int i = ty; i < 32; i += 8)
      tile[i][tx] = W[(size_t)(kb + i) * 1024 + nb + tx];
    __syncthreads();
    for (int i = ty; i < 32; i += 8)
      Wt[(size_t)(jb + i) * 3072 + kb + tx] = f2bf(tile[tx][i]);
  } else if (id < 34304) {                // prep_kv
    const int c = id - 33792;
    const float scale = g_v[c] * rsqrtf(var_v[c] + 1e-5f);
    for (int t = 0; t < 3; t++)
      for (int d = tid; d < 1024; d += 256)
        KVt[(size_t)c * 3072 + t * 1024 + d] = f2bf(Kv[(size_t)c * 3072 + d * 3 + t] * scale);
    if (tid == 0) biasv[c] = (bv[c] - mean_v[c]) * scale + beta_v[c];
  } else if (id < 35328) {                // prep_kn
    const int c = id - 34304;
    const float scale = g_n[c] * rsqrtf(var_n[c] + 1e-5f);
    for (int d = tid; d < 1024; d += 256)
      KNt[(size_t)c * 1024 + d] = f2bf(Kn[(size_t)c * 1024 + d] * scale);
    if (tid == 0) biasn[c] = (bnb[c] - mean_n[c]) * scale + beta_n[c];
  } else {                                // zero pad rows 0,65 of e1pad (B,66,D)
    const int i = (id - 35328) * 256 + tid;   // 0..262143
    const int b = i >> 11;
    const int j = i & 2047;
    const int r = (j < 1024) ? 0 : 65;
    const int d = j & 1023;
    e1pad[(size_t)(b * 66 + r) * 1024 + d] = 0;
  }
}

// ------------------------------------------------------------------ embed GEMM
// 128x128 C-tile, BK=64 (halved barrier count vs BK=32), 4 waves 2x2, each
// 64x64 via 4x4 mfma_f32_16x16x32_bf16 per k-half. LDS 2x16KB.
// XOR swizzle: chunk (row r, k-octet q) stored at index q ^ (r&7) within row
// -> fragment reads spread over all 8 bank groups (2-way only = free).
__global__ void gemm_embed(const u16* __restrict__ A, const u16* __restrict__ Bmat,
                           const float* __restrict__ bias0, const float* __restrict__ bias1,
                           const float* __restrict__ bias2,
                           float* __restrict__ oute1, float* __restrict__ oute2,
                           u16* __restrict__ e0bf, u16* __restrict__ e1pad,
                           u16* __restrict__ e2bf) {
  constexpr int K = 3072;
  __shared__ __align__(16) u16 As[128 * 64];   // 16 KB
  __shared__ __align__(16) u16 Bs[128 * 64];   // 16 KB

  const int tid = threadIdx.x;
  const int m0 = blockIdx.y * 128;
  const int n0 = blockIdx.x * 128;

  // staging: 4 A-chunks + 4 B-chunks per thread; chunk c = tid + i*256,
  // row = c>>3, stored octet q' = c&7, logical octet q = q' ^ (row&7)
  const u16* aSrc[4];
  const u16* bSrc[4];
#pragma unroll
  for (int i = 0; i < 4; i++) {
    const int c = tid + i * 256;
    const int row = c >> 3;
    const int q = (c & 7) ^ (row & 7);
    aSrc[i] = A + (size_t)(m0 + row) * 3072 + q * 8;
    bSrc[i] = Bmat + (size_t)(n0 + row) * 3072 + q * 8;
  }

  const int lane = tid & 63;
  const int warp = tid >> 6;
  const int wm = warp & 1, wn = warp >> 1;
  const int l15 = lane & 15, quad = lane >> 4;

  // fragment LDS pointers (k-invariant): per s-half and per frag index
  const u16* aF[2][4];
  const u16* bF[2][4];
#pragma unroll
  for (int s = 0; s < 2; s++)
#pragma unroll
    for (int i = 0; i < 4; i++) {
      const int ra = wm * 64 + i * 16 + l15;
      const int rb = wn * 64 + i * 16 + l15;
      aF[s][i] = &As[ra * 64 + ((s * 4 + quad) ^ (ra & 7)) * 8];
      bF[s][i] = &Bs[rb * 64 + ((s * 4 + quad) ^ (rb & 7)) * 8];
    }

  f32x4 acc[4][4];
#pragma unroll
  for (int i = 0; i < 4; i++)
#pragma unroll
    for (int j = 0; j < 4; j++) acc[i][j] = (f32x4){0.f, 0.f, 0.f, 0.f};

  for (int k0 = 0; k0 < K; k0 += 64) {
    __syncthreads();
#pragma unroll
    for (int i = 0; i < 4; i++) GLDS16(aSrc[i] + k0, &As[(tid + i * 256) * 8]);
#pragma unroll
    for (int i = 0; i < 4; i++) GLDS16(bSrc[i] + k0, &Bs[(tid + i * 256) * 8]);
    __syncthreads();

#pragma unroll
    for (int s = 0; s < 2; s++) {
      short8 fa[4], fb[4];
#pragma unroll
      for (int i = 0; i < 4; i++) fa[i] = *(const short8*)aF[s][i];
#pragma unroll
      for (int j = 0; j < 4; j++) fb[j] = *(const short8*)bF[s][j];
#pragma unroll
      for (int i = 0; i < 4; i++)
#pragma unroll
        for (int j = 0; j < 4; j++)
          acc[i][j] = __builtin_amdgcn_mfma_f32_16x16x32_bf16(fa[i], fb[j], acc[i][j], 0, 0, 0);
    }
  }

  const int w = n0 >> 10;
  const float* bp = (w == 0) ? bias0 : ((w == 1) ? bias1 : bias2);
#pragma unroll
  for (int i = 0; i < 4; i++) {
    const int mrow = m0 + wm * 64 + i * 16 + quad * 4;
#pragma unroll
    for (int j = 0; j < 4; j++) {
      const int c = n0 + wn * 64 + j * 16 + l15;
      const int n = c & 1023;
      const float bias = bp[n];
#pragma unroll
      for (int r = 0; r < 4; r++) {
        const int m = mrow + r;
        const float v = acc[i][j][r] + bias;
        if (w == 0) {
          e0bf[(size_t)m * 1024 + n] = f2bf(v);
        } else if (w == 1) {
          oute1[(size_t)m * 1024 + n] = v;
          const int bb = m >> 6, ll = m & 63;
          e1pad[(size_t)(bb * 66 + ll + 1) * 1024 + n] = f2bf(v);
        } else {
          oute2[(size_t)m * 1024 + n] = v;
          e2bf[(size_t)m * 1024 + n] = f2bf(v);
        }
      }
    }
  }
}

// -------------------------------------------- conv GEMM + in-epilogue top-k
// 64x128 tile (one batch per block), BK=64, 4 waves 1x4 along N: wave = 64x32.
// MODE 1: verb (A = e1pad im2col, K=3072, NC=512); MODE 2: noun (K=1024, NC=1024).
// Each wave covers all 64 l for its 32 columns -> in-register top-8 + quad merge.
template<int MODE>
__device__ __forceinline__ void conv_gemm_body(
    int bx, int by, const u16* __restrict__ A, const u16* __restrict__ Bmat,
    const float* __restrict__ bias, const int* __restrict__ lens,
    float* __restrict__ out, u16* As /*64x64*/, u16* Bs /*128x64*/) {
  constexpr int K = (MODE == 1) ? 3072 : 1024;
  constexpr int ldB = (MODE == 1) ? 3072 : 1024;
  constexpr int NC = (MODE == 1) ? 512 : 1024;

  const int tid = threadIdx.x;
  const int b = by;                 // batch
  const int n0 = bx * 128;

  // A staging: 2 chunks/thread (512 total); B: 4 chunks/thread (1024 total)
  int aRow[2], aQ[2];
#pragma unroll
  for (int i = 0; i < 2; i++) {
    const int c = tid + i * 256;
    aRow[i] = c >> 3;
    aQ[i] = ((c & 7) ^ (aRow[i] & 7)) * 8;
  }
  const u16* bSrc[4];
#pragma unroll
  for (int i = 0; i < 4; i++) {
    const int c = tid + i * 256;
    const int row = c >> 3;
    const int q = (c & 7) ^ (row & 7);
    bSrc[i] = Bmat + (size_t)(n0 + row) * ldB + q * 8;
  }

  const int lane = tid & 63;
  const int wn = tid >> 6;          // wave n-index, 0..3
  const int l15 = lane & 15, quad = lane >> 4;

  const u16* aF[2][4];
  const u16* bF[2][2];
#pragma unroll
  for (int s = 0; s < 2; s++) {
#pragma unroll
    for (int i = 0; i < 4; i++) {
      const int ra = i * 16 + l15;
      aF[s][i] = &As[ra * 64 + ((s * 4 + quad) ^ (ra & 7)) * 8];
    }
#pragma unroll
    for (int j = 0; j < 2; j++) {
      const int rb = wn * 32 + j * 16 + l15;
      bF[s][j] = &Bs[rb * 64 + ((s * 4 + quad) ^ (rb & 7)) * 8];
    }
  }

  f32x4 acc[4][2];
#pragma unroll
  for (int i = 0; i < 4; i++)
#pragma unroll
    for (int j = 0; j < 2; j++) acc[i][j] = (f32x4){0.f, 0.f, 0.f, 0.f};

  for (int k0 = 0; k0 < K; k0 += 64) {
    __syncthreads();
#pragma unroll
    for (int i = 0; i < 2; i++) {
      const u16* ga;
      if constexpr (MODE == 1) {
        const int t = k0 >> 10;                 // tap (never crosses within 64)
        const int kk = (k0 & 1023) + aQ[i];
        ga = A + (size_t)(b * 66 + aRow[i] + t) * 1024 + kk;
      } else {
        ga = A + (size_t)(b * 64 + aRow[i]) * 1024 + k0 + aQ[i];
      }
      GLDS16(ga, &As[(tid + i * 256) * 8]);
    }
#pragma unroll
    for (int i = 0; i < 4; i++) GLDS16(bSrc[i] + k0, &Bs[(tid + i * 256) * 8]);
    __syncthreads();

#pragma unroll
    for (int s = 0; s < 2; s++) {
      short8 fa[4], fb[2];
#pragma unroll
      for (int i = 0; i < 4; i++) fa[i] = *(const short8*)aF[s][i];
#pragma unroll
      for (int j = 0; j < 2; j++) fb[j] = *(const short8*)bF[s][j];
#pragma unroll
      for (int i = 0; i < 4; i++)
#pragma unroll
        for (int j = 0; j < 2; j++)
          acc[i][j] = __builtin_amdgcn_mfma_f32_16x16x32_bf16(fa[i], fb[j], acc[i][j], 0, 0, 0);
    }
  }

  // epilogue: sigmoid + per-column top-8 + mean of top-k
  const int len = lens[b];
  const int kk8 = (len + 7) >> 3;          // k = ceil(len/8), 1..8
#pragma unroll
  for (int j = 0; j < 2; j++) {
    const int c = n0 + wn * 32 + j * 16 + l15;
    const float bias_c = bias[c];
    float t[8];
#pragma unroll
    for (int q8 = 0; q8 < 8; q8++) t[q8] = -1e30f;
#pragma unroll
    for (int i = 0; i < 4; i++) {
#pragma unroll
      for (int r = 0; r < 4; r++) {
        const int l = i * 16 + quad * 4 + r;
        const float v = acc[i][j][r] + bias_c;
        const float sg = 1.0f / (1.0f + __expf(-v));
        float x = (l < len) ? sg : -1e30f;
#pragma unroll
        for (int q8 = 0; q8 < 8; q8++) {   // branchless sorted insert (desc)
          const float hi = fmaxf(t[q8], x);
          x = fminf(t[q8], x);
          t[q8] = hi;
        }
      }
    }
    // merge across quads (^16, ^32); snapshot partner list BEFORE inserting
#pragma unroll
    for (int mask = 16; mask <= 32; mask <<= 1) {
      float xs[8];
#pragma unroll
      for (int q8 = 0; q8 < 8; q8++) xs[q8] = __shfl_xor(t[q8], mask);
#pragma unroll
      for (int q8 = 0; q8 < 8; q8++) {
        float x = xs[q8];
#pragma unroll
        for (int p8 = 0; p8 < 8; p8++) {
          const float hi = fmaxf(t[p8], x);
          x = fminf(t[p8], x);
          t[p8] = hi;
        }
      }
    }
    if (quad == 0) {
      float s = 0.f;
#pragma unroll
      for (int q8 = 0; q8 < 8; q8++) s += (q8 < kk8) ? t[q8] : 0.f;
      out[(size_t)b * NC + c] = s / (float)kk8;
    }
  }
}

// fused tail: [0,512) verb GEMM+topk; [512,1536) noun GEMM+topk; [1536,1664) attn
__global__ void fused_tail(const u16* __restrict__ e1pad, const u16* __restrict__ KVt,
                           const float* __restrict__ biasv,
                           const u16* __restrict__ e2bf, const u16* __restrict__ KNt,
                           const float* __restrict__ biasn,
                           const u16* __restrict__ e0bf, const float* __restrict__ w_attn,
                           const float* __restrict__ b_attn, const int* __restrict__ lens,
                           float* __restrict__ out_sent, float* __restrict__ out_ilv,
                           float* __restrict__ out_iln) {
  __shared__ __align__(16) u16 smem[64 * 64 + 128 * 64];  // 24 KB
  u16* As = smem;
  u16* Bs = smem + 64 * 64;
  const int id = blockIdx.x;
  if (id < 512) {
    conv_gemm_body<1>(id & 3, id >> 2, e1pad, KVt, biasv, lens, out_ilv, As, Bs);
  } else if (id < 1536) {
    const int id2 = id - 512;
    conv_gemm_body<2>(id2 & 7, id2 >> 3, e2bf, KNt, biasn, lens, out_iln, As, Bs);
  } else {
    // ---- attention pooling, one block per batch
    const int b = id - 1536;
    const int tid = threadIdx.x;
    const int lane = tid & 63;
    const int warp = tid >> 6;
    float* sc = (float*)smem;        // 64 floats
    float* at = sc + 64;             // 64 floats
    const int len = lens[b];
    for (int t = 0; t < 16; t++) {
      const int l = warp * 16 + t;
      const u16* row = e0bf + (size_t)(b * 64 + l) * 1024;
      float s = 0.f;
#pragma unroll
      for (int u = 0; u < 16; u++) {
        const int d = lane + u * 64;
        s += bf2f(row[d]) * w_attn[d];
      }
#pragma unroll
      for (int off = 32; off > 0; off >>= 1) s += __shfl_down(s, off);
      if (lane == 0) sc[l] = s + b_attn[0];
    }
    __syncthreads();
    if (warp == 0) {
      float v = (lane < len) ? sc[lane] : -1e30f;
      float m = v;
#pragma unroll
      for (int off = 32; off > 0; off >>= 1) m = fmaxf(m, __shfl_xor(m, off));
      float p = (lane < len) ? __expf(v - m) : 0.f;
      float ssum = p;
#pragma unroll
      for (int off = 32; off > 0; off >>= 1) ssum += __shfl_xor(ssum, off);
      at[lane] = p / ssum;
    }
    __syncthreads();
    const int d0 = tid * 4;
    float a0 = 0.f, a1 = 0.f, a2 = 0.f, a3 = 0.f;
    for (int l = 0; l < 64; l++) {
      const float wgt = at[l];
      const ushort4 u4 = *(const ushort4*)(e0bf + (size_t)(b * 64 + l) * 1024 + d0);
      a0 += wgt * bf2f(u4.x);
      a1 += wgt * bf2f(u4.y);
      a2 += wgt * bf2f(u4.z);
      a3 += wgt * bf2f(u4.w);
    }
    float4 o; o.x = a0; o.y = a1; o.z = a2; o.w = a3;
    *(float4*)(out_sent + (size_t)b * 1024 + d0) = o;
  }
}

// --------------------------------------------------------------------- launch
extern "C" void kernel_launch(void* const* d_in, const int* in_sizes, int n_in,
                              void* d_out, int out_size, void* d_ws, size_t ws_size,
                              hipStream_t stream) {
  const float* inputs = (const float*)d_in[0];
  const int*   lens   = (const int*)d_in[1];
  const float* W0 = (const float*)d_in[2];
  const float* b0 = (const float*)d_in[3];
  const float* W1 = (const float*)d_in[4];
  const float* b1 = (const float*)d_in[5];
  const float* W2 = (const float*)d_in[6];
  const float* b2 = (const float*)d_in[7];
  const float* w_attn = (const float*)d_in[8];
  const float* b_attn = (const float*)d_in[9];
  const float* Kv   = (const float*)d_in[10];
  const float* bv   = (const float*)d_in[11];
  const float* g_v  = (const float*)d_in[12];
  const float* beta_v = (const float*)d_in[13];
  const float* mean_v = (const float*)d_in[14];
  const float* var_v  = (const float*)d_in[15];
  const float* Kn   = (const float*)d_in[16];
  const float* bn_b = (const float*)d_in[17];
  const float* g_n  = (const float*)d_in[18];
  const float* beta_n = (const float*)d_in[19];
  const float* mean_n = (const float*)d_in[20];
  const float* var_n  = (const float*)d_in[21];

  float* out = (float*)d_out;
  float* out_sent = out;                               // (128,1024)
  float* out_e1   = out + 131072;                      // (128,64,1024)
  float* out_e2   = out + 131072 + 8388608;            // (128,64,1024)
  float* out_ilv  = out + 131072 + 2 * 8388608;        // (128,512)
  float* out_iln  = out_ilv + 65536;                   // (128,1024)

  // workspace carve
  char* p = (char*)d_ws;
  u16* Xbf  = (u16*)p; p += (size_t)8192 * 3072 * 2;   // inputs bf16
  u16* Wt   = (u16*)p; p += (size_t)3072 * 3072 * 2;   // [W0|W1|W2]^T, N-major
  u16* KVt  = (u16*)p; p += (size_t)512 * 3072 * 2;    // verb weights, BN-folded
  u16* KNt  = (u16*)p; p += (size_t)1024 * 1024 * 2;   // noun weights, BN-folded
  float* biasv = (float*)p; p += 512 * 4;
  float* biasn = (float*)p; p += 1024 * 4;
  u16* e0bf  = (u16*)p; p += (size_t)8192 * 1024 * 2;
  u16* e1pad = (u16*)p; p += (size_t)128 * 66 * 1024 * 2;  // (B,66,D) zero-padded
  u16* e2bf  = (u16*)p; p += (size_t)8192 * 1024 * 2;

  prep_all<<<36352, 256, 0, stream>>>(inputs, Xbf, W0, W1, W2, Wt,
                                      Kv, bv, g_v, beta_v, mean_v, var_v, KVt, biasv,
                                      Kn, bn_b, g_n, beta_n, mean_n, var_n, KNt, biasn,
                                      e1pad);
  gemm_embed<<<dim3(24, 64), 256, 0, stream>>>(Xbf, Wt, b0, b1, b2, out_e1, out_e2,
                                               e0bf, e1pad, e2bf);
  fused_tail<<<1664, 256, 0, stream>>>(e1pad, KVt, biasv, e2bf, KNt, biasn,
                                       e0bf, w_attn, b_attn, lens,
                                       out_sent, out_ilv, out_iln);
}